// Round 1
// baseline (32.322 us; speedup 1.0000x reference)
//
#include <hip/hip_runtime.h>
#include <hip/hip_bf16.h>

#define NUM_SAMPLES 256
#define CH 64
#define IMG_H 512
#define IMG_W 512
#define BATCH 8

__device__ __forceinline__ float wave_reduce_sum(float v) {
    // full-wave (64-lane) butterfly; all lanes end with the total
    v += __shfl_xor(v, 32, 64);
    v += __shfl_xor(v, 16, 64);
    v += __shfl_xor(v, 8, 64);
    v += __shfl_xor(v, 4, 64);
    v += __shfl_xor(v, 2, 64);
    v += __shfl_xor(v, 1, 64);
    return v;
}

// One wave per (b, s): lane = channel.
__global__ void __launch_bounds__(64)
sample_diff_kernel(const float* __restrict__ fq,
                   const float* __restrict__ fk,
                   const int* __restrict__ ids,
                   float* __restrict__ partial) {
    const int c  = threadIdx.x;        // channel 0..63
    const int bs = blockIdx.x;         // 0..B*NUM_SAMPLES-1
    const int b  = bs >> 8;            // / NUM_SAMPLES
    const int s  = bs & (NUM_SAMPLES - 1);

    const int hi = ids[2 * s + 0];
    const int wi = ids[2 * s + 1];

    const size_t HW   = (size_t)IMG_H * IMG_W;
    const size_t base = ((size_t)(b * CH + c)) * HW + (size_t)hi * IMG_W + wi;

    // load 3x3 patch for both tensors (independent loads, issued together)
    float qv[9], kv[9];
#pragma unroll
    for (int r = 0; r < 3; ++r) {
#pragma unroll
        for (int col = 0; col < 3; ++col) {
            qv[r * 3 + col] = fq[base + (size_t)r * IMG_W + col];
            kv[r * 3 + col] = fk[base + (size_t)r * IMG_W + col];
        }
    }

    const float qc = qv[4];   // center (hi+1, wi+1)
    const float kc = kv[4];

    // neighbor flat indices in the 3x3 patch (skip center 4)
    const int nidx[8] = {0, 1, 2, 3, 5, 6, 7, 8};

    float dq[8], dk[8];
#pragma unroll
    for (int n = 0; n < 8; ++n) {
        dq[n] = qv[nidx[n]] - qc;
        dk[n] = kv[nidx[n]] - kc;
    }

    float rnq[8], rnk[8];
#pragma unroll
    for (int n = 0; n < 8; ++n) {
        const float sq = wave_reduce_sum(dq[n] * dq[n]);
        const float sk = wave_reduce_sum(dk[n] * dk[n]);
        rnq[n] = 1.0f / (sqrtf(sq) + 1e-7f);
        rnk[n] = 1.0f / (sqrtf(sk) + 1e-7f);
    }

    float acc = 0.0f;
#pragma unroll
    for (int n = 0; n < 8; ++n)
        acc += fabsf(dq[n] * rnq[n] - dk[n] * rnk[n]);

    acc = wave_reduce_sum(acc);
    if (c == 0) partial[bs] = acc;
}

__global__ void __launch_bounds__(256)
final_reduce_kernel(const float* __restrict__ partial, float* __restrict__ out) {
    __shared__ float sm[4];
    const int t = threadIdx.x;
    float v = 0.0f;
    for (int i = t; i < BATCH * NUM_SAMPLES; i += 256)
        v += partial[i];
    v = wave_reduce_sum(v);
    if ((t & 63) == 0) sm[t >> 6] = v;
    __syncthreads();
    if (t == 0) {
        const float tot = sm[0] + sm[1] + sm[2] + sm[3];
        // mean over B * C * NUM_SAMPLES * 8 = 8*64*256*8 = 1048576 elements
        out[0] = tot * (1.0f / 1048576.0f);
    }
}

extern "C" void kernel_launch(void* const* d_in, const int* in_sizes, int n_in,
                              void* d_out, int out_size, void* d_ws, size_t ws_size,
                              hipStream_t stream) {
    const float* fq  = (const float*)d_in[0];
    const float* fk  = (const float*)d_in[1];
    const int*   ids = (const int*)d_in[2];
    float* out     = (float*)d_out;
    float* partial = (float*)d_ws;   // needs B*NUM_SAMPLES*4 = 8 KB

    sample_diff_kernel<<<BATCH * NUM_SAMPLES, 64, 0, stream>>>(fq, fk, ids, partial);
    final_reduce_kernel<<<1, 256, 0, stream>>>(partial, out);
}